// Round 6
// baseline (127.195 us; speedup 1.0000x reference)
//
#include <hip/hip_runtime.h>
#include <hip/hip_fp16.h>

// BEV pooling: out[bin, c] = sum over points i with ranks_bev[i]==bin of
//                            depth_flat[ranks_depth[i]] * feat_flat[ranks_feat[i], c]
// ranks_bev SORTED. R6: gather is L2-scatter-granule bound (~3 cy/64B granule/CU
// model fits R2/R4/R5). Halve gather bytes: convert feat to fp16 per call
// (fused into prologue), 160B rows -> ~3 granule-touches/point instead of 5.
// Main kernel: one wave per bin, 16 point-slots x 4 lanes, 3 load passes,
// 24 fp32 acc/lane, xor-butterfly reduce, masked direct float4 stores.

#define CHN 80

// ---------------- prologue: seg starts + feat fp32->fp16 ----------------
__global__ __launch_bounds__(256)
void prologue_kernel(const int* __restrict__ rb, int* __restrict__ seg,
                     const float* __restrict__ feat, __half* __restrict__ feat16,
                     int P, int total_bev, int nfeat) {
    const int gid = blockIdx.x * blockDim.x + threadIdx.x;
    if (gid < nfeat) feat16[gid] = __float2half(feat[gid]);

    const int i4 = gid * 4;
    if (i4 >= P) return;
    const int4 v = *reinterpret_cast<const int4*>(rb + i4);
    int prev = (i4 == 0) ? -1 : rb[i4 - 1];
    int cur;
    cur = v.x; for (int b = prev + 1; b <= cur; ++b) seg[b] = i4 + 0; prev = cur;
    cur = v.y; for (int b = prev + 1; b <= cur; ++b) seg[b] = i4 + 1; prev = cur;
    cur = v.z; for (int b = prev + 1; b <= cur; ++b) seg[b] = i4 + 2; prev = cur;
    cur = v.w; for (int b = prev + 1; b <= cur; ++b) seg[b] = i4 + 3; prev = cur;
    if (i4 + 4 >= P) {
        for (int b = prev + 1; b <= total_bev; ++b) seg[b] = P;
    }
}

__device__ __forceinline__ void acc8(float* a, const uint4& u, float d) {
    const __half2* h = reinterpret_cast<const __half2*>(&u);
#pragma unroll
    for (int k = 0; k < 4; ++k) {
        const float2 f = __half22float2(h[k]);
        a[2 * k]     += d * f.x;
        a[2 * k + 1] += d * f.y;
    }
}

// ---------------- main kernel (fp16 feat) ----------------
__global__ __launch_bounds__(256)
void bev_pool_f16_kernel(const float* __restrict__ depth,
                         const __half* __restrict__ feat16,
                         const int* __restrict__ rd,
                         const int* __restrict__ rf,
                         const int* __restrict__ seg,
                         float* __restrict__ out,
                         int total_bev) {
    const int wave = threadIdx.x >> 6;               // 4 waves per block
    const int lane = threadIdx.x & 63;
    const int bin = blockIdx.x * 4 + wave;
    if (bin >= total_bev) return;

    const int slot = lane >> 2;                      // 0..15 point slot
    const int ll   = lane & 3;                       // 0..3 chunk lane

    const int lo = seg[bin];
    const int hi = seg[bin + 1];

    float a[24];                                     // ch ll*8.., 32+ll*8.., 64+ll*8..
#pragma unroll
    for (int k = 0; k < 24; ++k) a[k] = 0.f;

    int i = lo + slot;
    bool valid = i < hi;
    int di = 0, fi = 0;
    if (valid) { di = rd[i]; fi = rf[i]; }
    while (valid) {
        const int ni = i + 16;
        const bool nvalid = ni < hi;
        int ndi = 0, nfi = 0;
        if (nvalid) { ndi = rd[ni]; nfi = rf[ni]; }   // one-ahead index prefetch

        const float d = depth[di];
        const __half* row = feat16 + (size_t)fi * CHN;
        // pass0: halves [ll*8, +8)  -> lanes of a slot cover bytes 0..63 (1 granule)
        // pass1: halves [32+ll*8)   -> bytes 64..127
        // pass2: halves [64+ll*8), ll<2 only -> bytes 128..159
        const uint4 u0 = *reinterpret_cast<const uint4*>(row + ll * 8);
        const uint4 u1 = *reinterpret_cast<const uint4*>(row + 32 + ll * 8);
        uint4 u2 = make_uint4(0u, 0u, 0u, 0u);
        if (ll < 2) u2 = *reinterpret_cast<const uint4*>(row + 64 + ll * 8);

        acc8(a + 0,  u0, d);
        acc8(a + 8,  u1, d);
        acc8(a + 16, u2, d);

        i = ni; di = ndi; fi = nfi; valid = nvalid;
    }

    // Butterfly over the 16 slots (lane bits 2..5); same-ll lanes carry the
    // same channel set, so in-place xor reduce is exact.
#pragma unroll
    for (int ofs = 4; ofs <= 32; ofs <<= 1) {
#pragma unroll
        for (int k = 0; k < 24; ++k) a[k] += __shfl_xor(a[k], ofs, 64);
    }

    float* orow = out + (size_t)bin * CHN;
    if (lane < 4) {          // slot0: ll == lane -> ch ll*8..ll*8+7 and 32+..
        const int b0 = lane * 8;
        *reinterpret_cast<float4*>(orow + b0)          = make_float4(a[0],  a[1],  a[2],  a[3]);
        *reinterpret_cast<float4*>(orow + b0 + 4)      = make_float4(a[4],  a[5],  a[6],  a[7]);
        *reinterpret_cast<float4*>(orow + 32 + b0)     = make_float4(a[8],  a[9],  a[10], a[11]);
        *reinterpret_cast<float4*>(orow + 36 + b0)     = make_float4(a[12], a[13], a[14], a[15]);
    } else if (lane < 6) {   // slot1, ll = lane-4 in {0,1} -> ch 64+ll*8..
        const int b2 = (lane - 4) * 8;
        *reinterpret_cast<float4*>(orow + 64 + b2)     = make_float4(a[16], a[17], a[18], a[19]);
        *reinterpret_cast<float4*>(orow + 68 + b2)     = make_float4(a[20], a[21], a[22], a[23]);
    }
}

// ---------------- fallback (fp32, R5 structure) if ws too small ----------------
__global__ __launch_bounds__(256)
void seg_starts_kernel(const int* __restrict__ rb, int* __restrict__ seg,
                       int P, int total_bev) {
    int q = blockIdx.x * blockDim.x + threadIdx.x;
    int i4 = q * 4;
    if (i4 >= P) return;
    const int4 v = *reinterpret_cast<const int4*>(rb + i4);
    int prev = (i4 == 0) ? -1 : rb[i4 - 1];
    int cur;
    cur = v.x; for (int b = prev + 1; b <= cur; ++b) seg[b] = i4 + 0; prev = cur;
    cur = v.y; for (int b = prev + 1; b <= cur; ++b) seg[b] = i4 + 1; prev = cur;
    cur = v.z; for (int b = prev + 1; b <= cur; ++b) seg[b] = i4 + 2; prev = cur;
    cur = v.w; for (int b = prev + 1; b <= cur; ++b) seg[b] = i4 + 3; prev = cur;
    if (i4 + 4 >= P) {
        for (int b = prev + 1; b <= total_bev; ++b) seg[b] = P;
    }
}

__global__ __launch_bounds__(256)
void bev_pool_f32_kernel(const float* __restrict__ depth,
                         const float* __restrict__ feat,
                         const int* __restrict__ rd,
                         const int* __restrict__ rf,
                         const int* __restrict__ seg,
                         float* __restrict__ out,
                         int total_bev) {
    const int wave = threadIdx.x >> 6;
    const int lane = threadIdx.x & 63;
    const int bin = blockIdx.x * 4 + wave;
    if (bin >= total_bev) return;
    const int slot = lane >> 2;
    const int ll   = lane & 3;
    const int lo = seg[bin];
    const int hi = seg[bin + 1];
    float4 a0 = make_float4(0.f, 0.f, 0.f, 0.f);
    float4 a1 = a0, a2 = a0, a3 = a0, a4 = a0;
    int i = lo + slot;
    bool valid = i < hi;
    int di = 0, fi = 0;
    if (valid) { di = rd[i]; fi = rf[i]; }
    while (valid) {
        const int ni = i + 16;
        const bool nvalid = ni < hi;
        int ndi = 0, nfi = 0;
        if (nvalid) { ndi = rd[ni]; nfi = rf[ni]; }
        const float d = depth[di];
        const float4* frow = reinterpret_cast<const float4*>(feat + (size_t)fi * CHN) + ll;
        const float4 f0 = frow[0], f1 = frow[4], f2 = frow[8], f3 = frow[12], f4 = frow[16];
        a0.x += d * f0.x; a0.y += d * f0.y; a0.z += d * f0.z; a0.w += d * f0.w;
        a1.x += d * f1.x; a1.y += d * f1.y; a1.z += d * f1.z; a1.w += d * f1.w;
        a2.x += d * f2.x; a2.y += d * f2.y; a2.z += d * f2.z; a2.w += d * f2.w;
        a3.x += d * f3.x; a3.y += d * f3.y; a3.z += d * f3.z; a3.w += d * f3.w;
        a4.x += d * f4.x; a4.y += d * f4.y; a4.z += d * f4.z; a4.w += d * f4.w;
        i = ni; di = ndi; fi = nfi; valid = nvalid;
    }
#pragma unroll
    for (int ofs = 4; ofs <= 32; ofs <<= 1) {
        a0.x += __shfl_xor(a0.x, ofs, 64); a0.y += __shfl_xor(a0.y, ofs, 64);
        a0.z += __shfl_xor(a0.z, ofs, 64); a0.w += __shfl_xor(a0.w, ofs, 64);
        a1.x += __shfl_xor(a1.x, ofs, 64); a1.y += __shfl_xor(a1.y, ofs, 64);
        a1.z += __shfl_xor(a1.z, ofs, 64); a1.w += __shfl_xor(a1.w, ofs, 64);
        a2.x += __shfl_xor(a2.x, ofs, 64); a2.y += __shfl_xor(a2.y, ofs, 64);
        a2.z += __shfl_xor(a2.z, ofs, 64); a2.w += __shfl_xor(a2.w, ofs, 64);
        a3.x += __shfl_xor(a3.x, ofs, 64); a3.y += __shfl_xor(a3.y, ofs, 64);
        a3.z += __shfl_xor(a3.z, ofs, 64); a3.w += __shfl_xor(a3.w, ofs, 64);
        a4.x += __shfl_xor(a4.x, ofs, 64); a4.y += __shfl_xor(a4.y, ofs, 64);
        a4.z += __shfl_xor(a4.z, ofs, 64); a4.w += __shfl_xor(a4.w, ofs, 64);
    }
    if (lane < 20) {
        const int j = lane >> 2;
        float4 w = a0;
        if (j == 1) w = a1;
        else if (j == 2) w = a2;
        else if (j == 3) w = a3;
        else if (j == 4) w = a4;
        *reinterpret_cast<float4*>(out + (size_t)bin * CHN + lane * 4) = w;
    }
}

extern "C" void kernel_launch(void* const* d_in, const int* in_sizes, int n_in,
                              void* d_out, int out_size, void* d_ws, size_t ws_size,
                              hipStream_t stream) {
    const float* depth = (const float*)d_in[0];
    const float* feat  = (const float*)d_in[1];
    const int*   rd    = (const int*)d_in[2];
    const int*   rf    = (const int*)d_in[3];
    const int*   rb    = (const int*)d_in[4];
    float* out = (float*)d_out;

    const int P = in_sizes[2];
    const int nfeat = in_sizes[1];            // 337920
    const int total_bev = out_size / CHN;     // 40000

    const size_t seg_bytes = ((size_t)(total_bev + 1) * 4 + 15) & ~(size_t)15;
    const size_t need = seg_bytes + (size_t)nfeat * 2;

    int* seg = (int*)d_ws;
    const int quads = (P + 3) / 4;
    const int quad_blocks = (quads + 255) / 256;

    if (ws_size >= need) {
        __half* feat16 = (__half*)((char*)d_ws + seg_bytes);
        const int cvt_blocks = (nfeat + 255) / 256;
        const int pro_blocks = quad_blocks > cvt_blocks ? quad_blocks : cvt_blocks;
        prologue_kernel<<<pro_blocks, 256, 0, stream>>>(rb, seg, feat, feat16,
                                                        P, total_bev, nfeat);
        bev_pool_f16_kernel<<<(total_bev + 3) / 4, 256, 0, stream>>>(
            depth, feat16, rd, rf, seg, out, total_bev);
    } else {
        seg_starts_kernel<<<quad_blocks, 256, 0, stream>>>(rb, seg, P, total_bev);
        bev_pool_f32_kernel<<<(total_bev + 3) / 4, 256, 0, stream>>>(
            depth, feat, rd, rf, seg, out, total_bev);
    }
}

// Round 7
// 119.684 us; speedup vs baseline: 1.0628x; 1.0628x over previous
//
#include <hip/hip_runtime.h>

// BEV pooling: out[bin, c] = sum over points i with ranks_bev[i]==bin of
//                            depth_flat[ranks_depth[i]] * feat_flat[ranks_feat[i], c]
// ranks_bev SORTED. Phase 1: seg[b] = lower_bound(rb, b) by boundary detection.
// Phase 2: one wave per bin, 16 point-slots x 4 channel-lanes (float4), with a
// DEPTH-2 SOFTWARE PIPELINE: idx two iterations ahead, data (depth + 5x float4
// feat) one iteration ahead -> the L2 gather latency sits under the previous
// iteration's FMAs instead of stalling every iteration (R6 showed the exposed
// per-iter load->FMA chain is the binder; byte reduction bought nothing).

#define CHN 80

__global__ __launch_bounds__(256)
void seg_starts_kernel(const int* __restrict__ rb, int* __restrict__ seg,
                       int P, int total_bev) {
    int q = blockIdx.x * blockDim.x + threadIdx.x;   // quad index
    int i4 = q * 4;
    if (i4 >= P) return;
    const int4 v = *reinterpret_cast<const int4*>(rb + i4);
    int prev = (i4 == 0) ? -1 : rb[i4 - 1];
    int cur;
    cur = v.x; for (int b = prev + 1; b <= cur; ++b) seg[b] = i4 + 0; prev = cur;
    cur = v.y; for (int b = prev + 1; b <= cur; ++b) seg[b] = i4 + 1; prev = cur;
    cur = v.z; for (int b = prev + 1; b <= cur; ++b) seg[b] = i4 + 2; prev = cur;
    cur = v.w; for (int b = prev + 1; b <= cur; ++b) seg[b] = i4 + 3; prev = cur;
    if (i4 + 4 >= P) {
        for (int b = prev + 1; b <= total_bev; ++b) seg[b] = P;
    }
}

__global__ __launch_bounds__(256)
void bev_pool_kernel(const float* __restrict__ depth,
                     const float* __restrict__ feat,
                     const int* __restrict__ rd,
                     const int* __restrict__ rf,
                     const int* __restrict__ seg,
                     float* __restrict__ out,
                     int total_bev) {
    const int wave = threadIdx.x >> 6;               // 4 waves per block
    const int lane = threadIdx.x & 63;
    const int bin = blockIdx.x * 4 + wave;
    if (bin >= total_bev) return;

    const int slot = lane >> 2;                      // 0..15 point slot
    const int ll   = lane & 3;                       // 0..3 channel sub-lane

    const int lo = seg[bin];
    const int hi = seg[bin + 1];

    float4 a0 = make_float4(0.f, 0.f, 0.f, 0.f);
    float4 a1 = a0, a2 = a0, a3 = a0, a4 = a0;

    // ---- pipeline preamble: idx for k=0 and k=1, data for k=0 ----
    int i0 = lo + slot;
    bool v0 = i0 < hi;
    int di0 = 0, fi0 = 0;
    if (v0) { di0 = rd[i0]; fi0 = rf[i0]; }

    int i1 = i0 + 16;
    bool v1 = i1 < hi;
    int di1 = 0, fi1 = 0;
    if (v1) { di1 = rd[i1]; fi1 = rf[i1]; }

    float d0 = 0.f;
    float4 f00 = make_float4(0.f, 0.f, 0.f, 0.f), f01 = f00, f02 = f00, f03 = f00, f04 = f00;
    if (v0) {
        d0 = depth[di0];
        const float4* r = reinterpret_cast<const float4*>(feat + (size_t)fi0 * CHN) + ll;
        f00 = r[0]; f01 = r[4]; f02 = r[8]; f03 = r[12]; f04 = r[16];
    }

    while (v0) {
        // issue data loads for k+1 (independent of k's data)
        float d1 = 0.f;
        float4 f10 = make_float4(0.f, 0.f, 0.f, 0.f), f11 = f10, f12 = f10, f13 = f10, f14 = f10;
        if (v1) {
            d1 = depth[di1];
            const float4* r = reinterpret_cast<const float4*>(feat + (size_t)fi1 * CHN) + ll;
            f10 = r[0]; f11 = r[4]; f12 = r[8]; f13 = r[12]; f14 = r[16];
        }
        // issue idx loads for k+2
        const int i2 = i1 + 16;
        const bool v2 = i2 < hi;
        int di2 = 0, fi2 = 0;
        if (v2) { di2 = rd[i2]; fi2 = rf[i2]; }

        // accumulate k (waits only on k's loads; k+1's stay in flight)
        a0.x += d0 * f00.x; a0.y += d0 * f00.y; a0.z += d0 * f00.z; a0.w += d0 * f00.w;
        a1.x += d0 * f01.x; a1.y += d0 * f01.y; a1.z += d0 * f01.z; a1.w += d0 * f01.w;
        a2.x += d0 * f02.x; a2.y += d0 * f02.y; a2.z += d0 * f02.z; a2.w += d0 * f02.w;
        a3.x += d0 * f03.x; a3.y += d0 * f03.y; a3.z += d0 * f03.z; a3.w += d0 * f03.w;
        a4.x += d0 * f04.x; a4.y += d0 * f04.y; a4.z += d0 * f04.z; a4.w += d0 * f04.w;

        // shift pipeline
        d0 = d1; f00 = f10; f01 = f11; f02 = f12; f03 = f13; f04 = f14;
        v0 = v1; v1 = v2; i1 = i2; di1 = di2; fi1 = fi2;
    }

    // Butterfly reduce across the 16 slots (lane bits 2..5); xor butterfly is
    // self-symmetric so in-place += is exact.
#pragma unroll
    for (int ofs = 4; ofs <= 32; ofs <<= 1) {
        a0.x += __shfl_xor(a0.x, ofs, 64); a0.y += __shfl_xor(a0.y, ofs, 64);
        a0.z += __shfl_xor(a0.z, ofs, 64); a0.w += __shfl_xor(a0.w, ofs, 64);
        a1.x += __shfl_xor(a1.x, ofs, 64); a1.y += __shfl_xor(a1.y, ofs, 64);
        a1.z += __shfl_xor(a1.z, ofs, 64); a1.w += __shfl_xor(a1.w, ofs, 64);
        a2.x += __shfl_xor(a2.x, ofs, 64); a2.y += __shfl_xor(a2.y, ofs, 64);
        a2.z += __shfl_xor(a2.z, ofs, 64); a2.w += __shfl_xor(a2.w, ofs, 64);
        a3.x += __shfl_xor(a3.x, ofs, 64); a3.y += __shfl_xor(a3.y, ofs, 64);
        a3.z += __shfl_xor(a3.z, ofs, 64); a3.w += __shfl_xor(a3.w, ofs, 64);
        a4.x += __shfl_xor(a4.x, ofs, 64); a4.y += __shfl_xor(a4.y, ofs, 64);
        a4.z += __shfl_xor(a4.z, ofs, 64); a4.w += __shfl_xor(a4.w, ofs, 64);
    }

    // Lane L (< 20) stores chunk L = j*4 + ll with j = L>>2  ->  its a[j].
    if (lane < 20) {
        const int j = lane >> 2;
        float4 w = a0;
        if (j == 1) w = a1;
        else if (j == 2) w = a2;
        else if (j == 3) w = a3;
        else if (j == 4) w = a4;
        *reinterpret_cast<float4*>(out + (size_t)bin * CHN + lane * 4) = w;
    }
}

extern "C" void kernel_launch(void* const* d_in, const int* in_sizes, int n_in,
                              void* d_out, int out_size, void* d_ws, size_t ws_size,
                              hipStream_t stream) {
    const float* depth = (const float*)d_in[0];
    const float* feat  = (const float*)d_in[1];
    const int*   rd    = (const int*)d_in[2];
    const int*   rf    = (const int*)d_in[3];
    const int*   rb    = (const int*)d_in[4];
    // d_in[5], d_in[6] (interval_starts/lengths) unused per reference; d_in[7] scalar total_bev.
    float* out = (float*)d_out;

    const int P = in_sizes[2];
    const int total_bev = out_size / CHN;   // 40000

    int* seg = (int*)d_ws;                  // total_bev+1 ints, rewritten fully every call

    const int quads = (P + 3) / 4;
    seg_starts_kernel<<<(quads + 255) / 256, 256, 0, stream>>>(rb, seg, P, total_bev);
    bev_pool_kernel<<<(total_bev + 3) / 4, 256, 0, stream>>>(depth, feat, rd, rf, seg,
                                                             out, total_bev);
}